// Round 3
// baseline (578.589 us; speedup 1.0000x reference)
//
#include <hip/hip_runtime.h>
#include <math.h>

#define Bb 8
#define Nn 64
#define Ff 32
#define Tt 4
#define OUTn 128
#define NPAIR 2016   // 64*63/2 lower-triangle pairs (i>j)

__device__ __forceinline__ float sigmoidf_(float x){ return 1.0f/(1.0f+expf(-x)); }

__device__ __forceinline__ int pidx(int hi, int lo){ return hi*(hi-1)/2 + lo; }

__device__ __forceinline__ void p2ij(int p, int& i, int& j){
  int ii = (int)((1.0f + sqrtf(1.0f + 8.0f*(float)p)) * 0.5f);
  while (ii*(ii-1)/2 > p) --ii;
  while ((ii+1)*ii/2 <= p) ++ii;
  i = ii; j = p - ii*(ii-1)/2;
}

__device__ __forceinline__ float dot32(const float4* __restrict__ u, const float* __restrict__ v){
  const float4* v4 = (const float4*)v;
  float d = 0.f;
#pragma unroll
  for (int q=0;q<8;++q){
    float4 a=u[q], b=v4[q];
    d = fmaf(a.x,b.x,d); d = fmaf(a.y,b.y,d);
    d = fmaf(a.z,b.z,d); d = fmaf(a.w,b.w,d);
  }
  return d;
}

// ---- per-pair precompute: wzxb/wcxb for all 8 b, uznorm. Pairs i>j only. ----
__global__ __launch_bounds__(64) void precompute_pair(
    const float* __restrict__ x,
    const float* __restrict__ w_z,
    const float* __restrict__ w_c,
    const float* __restrict__ u_z,
    const float* __restrict__ b_z,
    const float* __restrict__ b_c,
    float* __restrict__ wzxb,
    float* __restrict__ wcxb,
    float* __restrict__ uzn) {
  int p = blockIdx.x;
  int i, j; p2ij(p, i, j);
  int l = threadIdx.x, f = l & 31, h = l >> 5;

  __shared__ __align__(16) float xL[Bb][Ff];
  for (int q = l; q < Bb*Ff; q += 64) {
    int b = q >> 5, g = q & 31;
    xL[b][g] = x[(b*Nn + i)*Ff + g];
  }
  __syncthreads();

  size_t rowoff = (((size_t)i*Nn + j)*Ff + f)*Ff;
  {
    const float4* w4 = (const float4*)&w_z[rowoff];
    float4 w[8];
#pragma unroll
    for (int q=0;q<8;++q) w[q]=w4[q];
    float bz = b_z[f];
#pragma unroll
    for (int bb=0;bb<4;++bb){
      int b = h*4+bb;
      wzxb[(size_t)p*256 + b*32 + f] = dot32(w, xL[b]) + bz;
    }
  }
  {
    const float4* w4 = (const float4*)&w_c[rowoff];
    float4 w[8];
#pragma unroll
    for (int q=0;q<8;++q) w[q]=w4[q];
    float bc = b_c[f];
#pragma unroll
    for (int bb=0;bb<4;++bb){
      int b = h*4+bb;
      wcxb[(size_t)p*256 + b*32 + f] = dot32(w, xL[b]) + bc;
    }
  }
  if (h == 0) {
    const float4* u4 = (const float4*)&u_z[rowoff];
    float ss = 0.f;
#pragma unroll
    for (int q=0;q<8;++q){
      float4 v = u4[q];
      ss = fmaf(v.x,v.x,ss); ss = fmaf(v.y,v.y,ss);
      ss = fmaf(v.z,v.z,ss); ss = fmaf(v.w,v.w,ss);
    }
    uzn[(size_t)p*32 + f] = sqrtf(ss);
  }
}

// ---- one MP iteration, one wave per (i>j) pair, all 8 b per wave ----
__global__ __launch_bounds__(64) void pair_update(
    const float* __restrict__ A,
    const float* __restrict__ u_z,
    const float* __restrict__ u_c,
    const float* __restrict__ wzxb,
    const float* __restrict__ wcxb,
    const float* __restrict__ uzn,
    const float* __restrict__ agg,
    const float* __restrict__ mnmax,
    const float* __restrict__ mfp,
    float* __restrict__ mfn,
    int first) {
  int p = blockIdx.x;
  int i, j; p2ij(p, i, j);
  int l = threadIdx.x, f = l & 31, h = l >> 5;

  __shared__ __align__(16) float moL[Bb][Ff];
  __shared__ __align__(16) float gsL[Bb][Ff];
  __shared__ __align__(16) float rmL[Bb][Ff];

  // stage m_other[b,:] = agg[b,i,:] - A[b,i,j]*mf_prev[p][b,:]
  for (int q = l; q < Bb*Ff; q += 64) {
    int b = q >> 5, g = q & 31;
    float mo = 0.f;
    if (!first) {
      float a  = A[(b*Nn + i)*Nn + j];
      float mv = a * mfp[(size_t)p*256 + b*32 + g];
      mo = agg[(b*Nn + i)*Ff + g] - mv;
    }
    moL[b][g] = mo;
  }
  __syncthreads();

  // u_z row in registers (reused for all 8 b and for the rare gate path)
  const float4* uz4 = (const float4*)&u_z[(((size_t)i*Nn + j)*Ff + f)*Ff];
  float4 u[8];
#pragma unroll
  for (int q=0;q<8;++q) u[q]=uz4[q];

  float un = first ? 0.f : uzn[(size_t)p*32 + f];

  float zv[4], wbR[4];
  bool need = false;
#pragma unroll
  for (int bb=0;bb<4;++bb){
    int b = h*4+bb;
    float wb = wzxb[(size_t)p*256 + b*32 + f];
    wbR[bb] = wb;
    float d = dot32(u, moL[b]);
    zv[bb] = sigmoidf_(wb + d);
    if (!first) {
      float mm = mnmax[b*Nn + i];
      if (wb + un*mm >= 15.5f) need = true;
    }
  }

  // rare exact-gate path (Cauchy-Schwarz screen failed for some (b,f))
  float d2[4] = {0.f,0.f,0.f,0.f};
  if (__any(need)) {
#pragma unroll 1
    for (int bb=0;bb<4;++bb){
      int b = h*4+bb;
      float wb = wbR[bb];
      float gv = 0.f;
      for (int k=0;k<Nn;++k){
        if (k == j) continue;
        float a = A[(b*Nn + i)*Nn + k];
        if (a == 0.0f) continue;
        int hi2 = i > k ? i : k, lo2 = i > k ? k : i;
        const float* Mr = &mfp[(size_t)pidx(hi2,lo2)*256 + b*32];
        float dd = dot32(u, Mr);
        float v = wb + dd;
        if (v >= 16.0f && (v > 17.5f || sigmoidf_(v) >= 1.0f)) gv += Mr[f];
      }
      gsL[b][f] = gv;
    }
    __syncthreads();
    const float4* uc4 = (const float4*)&u_c[(((size_t)i*Nn + j)*Ff + f)*Ff];
    float4 uc[8];
#pragma unroll
    for (int q=0;q<8;++q) uc[q]=uc4[q];
#pragma unroll 1
    for (int bb=0;bb<4;++bb){
      int b = h*4+bb;
      rmL[b][f] = dot32(uc, gsL[b]);
    }
    __syncthreads();
#pragma unroll 1
    for (int bb=0;bb<4;++bb){
      int b = h*4+bb;
      d2[bb] = dot32(uc, rmL[b]);
    }
  }

  // m_full = (1-z)*m_other + z*tanh(wcxb + d2)
#pragma unroll
  for (int bb=0;bb<4;++bb){
    int b = h*4+bb;
    float wc = wcxb[(size_t)p*256 + b*32 + f];
    float curv = tanhf(wc + d2[bb]);
    float z = zv[bb];
    mfn[(size_t)p*256 + b*32 + f] = (1.0f - z)*moL[b][f] + z*curv;
  }
}

// ---- per (b,i): agg[f] = sum_k M[b,i,k,f], mnmax = max_k ||M row|| ----
__global__ __launch_bounds__(64) void gather_agg(
    const float* __restrict__ A,
    const float* __restrict__ mf,
    float* __restrict__ agg,
    float* __restrict__ mnmax) {
  int bi = blockIdx.x;
  int b = bi >> 6, i = bi & 63;
  int l = threadIdx.x, f = l & 31, h = l >> 5;

  float a = A[(b*Nn + i)*Nn + l];
  unsigned long long mask = __ballot(a != 0.0f);

  float acc = 0.f, mx2 = 0.f;
  unsigned long long mm = mask;
  int idx = 0;
  while (mm) {
    int k = __builtin_ctzll(mm);
    mm &= mm - 1;
    if ((idx & 1) == h) {
      int hi2 = i > k ? i : k, lo2 = i > k ? k : i;
      const float* Mr = &mf[(size_t)pidx(hi2,lo2)*256 + b*32];
      float v = Mr[f];
      acc += v;
      float ss = v*v;
      ss += __shfl_xor(ss, 1);  ss += __shfl_xor(ss, 2);
      ss += __shfl_xor(ss, 4);  ss += __shfl_xor(ss, 8);
      ss += __shfl_xor(ss, 16);
      mx2 = fmaxf(mx2, ss);
    }
    idx++;
  }
  float accO = __shfl(acc, l ^ 32);
  float mxO  = __shfl(mx2, l ^ 32);
  if (l < 32) agg[(b*Nn + i)*Ff + f] = acc + accO;
  if (l == 0) mnmax[b*Nn + i] = sqrtf(fmaxf(mx2, mxO));
}

// ---- enc = relu(u_node.x + u_msg.msg_sum)  (msg_sum == agg after last iter) ----
__global__ __launch_bounds__(64) void finalize_enc(
    const float* __restrict__ x,
    const float* __restrict__ agg,
    const float* __restrict__ u_node,
    const float* __restrict__ u_msg,
    float* __restrict__ enc) {
  int bi = blockIdx.x;
  int b = bi >> 6, i = bi & 63;
  int l = threadIdx.x, f = l & 31, h = l >> 5;
  __shared__ __align__(16) float vecL[2][Ff];
  if (l < 32)      vecL[0][l]      = x[(b*Nn + i)*Ff + l];
  else             vecL[1][l - 32] = agg[(b*Nn + i)*Ff + (l - 32)];
  __syncthreads();
  const float* Urow = (h == 0) ? &u_node[((size_t)i*Ff + f)*Ff]
                               : &u_msg [((size_t)i*Ff + f)*Ff];
  float4 w[8];
  const float4* w4 = (const float4*)Urow;
#pragma unroll
  for (int q=0;q<8;++q) w[q]=w4[q];
  float d = dot32(w, vecL[h]);
  float dO = __shfl(d, l ^ 32);
  if (l < 32) enc[(b*Nn + i)*Ff + f] = fmaxf(d + dO, 0.0f);
}

// ---- output linear + sigmoid ----
__global__ void linear_out(const float* __restrict__ enc,
                           const float* __restrict__ lin_w,
                           const float* __restrict__ lin_b,
                           float* __restrict__ out) {
  int b = blockIdx.x;   // 8
  int o = threadIdx.x;  // 128
  __shared__ __align__(16) float eL[Nn*Ff];
  for (int c = o; c < Nn*Ff; c += 128) eL[c] = enc[b*Nn*Ff + c];
  __syncthreads();
  float acc = lin_b[o];
  const float4* w4 = (const float4*)&lin_w[(size_t)o*Nn*Ff];
  const float4* e4 = (const float4*)eL;
  for (int q = 0; q < (Nn*Ff)/4; ++q) {
    float4 w = w4[q], e = e4[q];
    acc = fmaf(w.x,e.x,acc); acc = fmaf(w.y,e.y,acc);
    acc = fmaf(w.z,e.z,acc); acc = fmaf(w.w,e.w,acc);
  }
  out[b*OUTn + o] = 1.0f/(1.0f+expf(-acc));
}

extern "C" void kernel_launch(void* const* d_in, const int* in_sizes, int n_in,
                              void* d_out, int out_size, void* d_ws, size_t ws_size,
                              hipStream_t stream) {
  const float* x      = (const float*)d_in[0];
  const float* A      = (const float*)d_in[1];
  const float* w_z    = (const float*)d_in[2];
  const float* w_c    = (const float*)d_in[3];
  const float* u_z    = (const float*)d_in[4];
  const float* u_c    = (const float*)d_in[5];
  const float* b_z    = (const float*)d_in[6];
  const float* b_c    = (const float*)d_in[7];
  const float* u_node = (const float*)d_in[8];
  const float* u_msg  = (const float*)d_in[9];
  const float* lin_w  = (const float*)d_in[10];
  const float* lin_b  = (const float*)d_in[11];
  float* out = (float*)d_out;
  float* ws  = (float*)d_ws;

  const size_t PB = (size_t)NPAIR * 256;   // 516096 floats per pair-array
  float* wzxb = ws;
  float* wcxb = wzxb + PB;
  float* uzn  = wcxb + PB;                 // NPAIR*32
  float* mf0  = uzn  + (size_t)NPAIR*32;
  float* mf1  = mf0  + PB;
  float* agg  = mf1  + PB;                 // 8*64*32
  float* mnmx = agg  + (size_t)Bb*Nn*Ff;   // 8*64
  float* enc  = mnmx + (size_t)Bb*Nn;      // 8*64*32

  precompute_pair<<<NPAIR, 64, 0, stream>>>(x, w_z, w_c, u_z, b_z, b_c,
                                            wzxb, wcxb, uzn);

  float* rd = mf0; float* wr = mf1;
  for (int t = 0; t < Tt; ++t) {
    pair_update<<<NPAIR, 64, 0, stream>>>(A, u_z, u_c, wzxb, wcxb, uzn,
                                          agg, mnmx, rd, wr, t == 0 ? 1 : 0);
    gather_agg<<<Bb*Nn, 64, 0, stream>>>(A, wr, agg, mnmx);
    float* tmp = rd; rd = wr; wr = tmp;
  }
  // agg now holds msg_sum of the final M
  finalize_enc<<<Bb*Nn, 64, 0, stream>>>(x, agg, u_node, u_msg, enc);
  linear_out<<<Bb, 128, 0, stream>>>(enc, lin_w, lin_b, out);
}

// Round 4
// 178.963 us; speedup vs baseline: 3.2330x; 3.2330x over previous
//
#include <hip/hip_runtime.h>
#include <math.h>

#define Bb 8
#define Nn 64
#define Ff 32
#define Tt 4
#define OUTn 128
#define NPAIR 2016   // 64*63/2 lower-triangle pairs (i>j)

__device__ __forceinline__ float sigmoidf_(float x){ return 1.0f/(1.0f+expf(-x)); }

__device__ __forceinline__ void p2ij(int p, int& i, int& j){
  int ii = (int)((1.0f + sqrtf(1.0f + 8.0f*(float)p)) * 0.5f);
  while (ii*(ii-1)/2 > p) --ii;
  while ((ii+1)*ii/2 <= p) ++ii;
  i = ii; j = p - ii*(ii-1)/2;
}

// sequential-order fp32 dot (bit-identical to the validated round-0 ordering)
__device__ __forceinline__ float dot32(const float4* __restrict__ u, const float* __restrict__ v){
  const float4* v4 = (const float4*)v;
  float d = 0.f;
#pragma unroll
  for (int q=0;q<8;++q){
    float4 a=u[q], b=v4[q];
    d = fmaf(a.x,b.x,d); d = fmaf(a.y,b.y,d);
    d = fmaf(a.z,b.z,d); d = fmaf(a.w,b.w,d);
  }
  return d;
}

// ---- precompute wzxb/wcxb for lower-tri pairs, all 8 b ----
__global__ __launch_bounds__(64) void precompute_pair(
    const float* __restrict__ x,
    const float* __restrict__ w_z,
    const float* __restrict__ w_c,
    const float* __restrict__ b_z,
    const float* __restrict__ b_c,
    float* __restrict__ wzxb,
    float* __restrict__ wcxb) {
  int p = blockIdx.x;
  int i, j; p2ij(p, i, j);
  int l = threadIdx.x, f = l & 31, h = l >> 5;

  __shared__ __align__(16) float xL[Bb][Ff];
  for (int q = l; q < Bb*Ff; q += 64) {
    int b = q >> 5, g = q & 31;
    xL[b][g] = x[(b*Nn + i)*Ff + g];
  }
  __syncthreads();

  const float* W = h ? w_c : w_z;
  const float4* w4 = (const float4*)&W[(((size_t)i*Nn + j)*Ff + f)*Ff];
  float4 w[8];
#pragma unroll
  for (int q=0;q<8;++q) w[q]=w4[q];
  float bias = h ? b_c[f] : b_z[f];
  float* dst = h ? wcxb : wzxb;
#pragma unroll
  for (int b=0;b<Bb;++b){
    dst[((size_t)(b*Nn + i)*Nn + j)*Ff + f] = dot32(w, xL[b]) + bias;
  }
}

// ---- one MP iteration over lower-tri edges; block = (b, i, j-half) ----
__global__ __launch_bounds__(256) void edge_update(
    const float* __restrict__ A,
    const float* __restrict__ u_z,
    const float* __restrict__ u_c,
    const float* __restrict__ wzxb,
    const float* __restrict__ wcxb,
    const float* __restrict__ mfp,
    float* __restrict__ mfn,
    int first) {
  int b  = blockIdx.x;   // 8
  int i  = blockIdx.y;   // 64
  int jh = blockIdx.z;   // 2
  int tid = threadIdx.x;

  __shared__ __align__(16) float Mc [Nn][Ff];
  __shared__ __align__(16) float moL[32][Ff];
  __shared__ __align__(16) float gsL[32][Ff];
  __shared__ __align__(16) float rmL[32][Ff];
  __shared__ float aggL[Ff];
  __shared__ int nbrL[Nn];
  __shared__ int jlistL[32], jslotL[32];
  __shared__ int nnL, jcL;

  if (tid < 64) {
    float a = A[(b*Nn + i)*Nn + tid];
    bool e = (a != 0.0f);
    unsigned long long m = __ballot(e);
    if (e) nbrL[__popcll(m & ((1ull << tid) - 1ull))] = tid;
    bool ej = e && (tid < i);
    unsigned long long mj = __ballot(ej);
    if (ej) {
      int r = __popcll(mj & ((1ull << tid) - 1ull));   // rank among valid j's
      if ((r & 1) == jh) {
        int jl = r >> 1;
        jlistL[jl] = tid;
        jslotL[jl] = __popcll(m & ((1ull << tid) - 1ull));
      }
    }
    if (tid == 0) {
      nnL = __popcll(m);
      int jct = __popcll(mj);
      jcL = (jct + 1 - jh) >> 1;   // jh=0: ceil, jh=1: floor
    }
  }
  __syncthreads();
  int nn = nnL, jc = jcL;
  if (jc == 0) return;
  int P = jc * Ff;

  if (!first) {
    for (int q = tid; q < nn*Ff; q += 256) {
      int s = q >> 5, f = q & 31;
      int k = nbrL[s];
      int hi = i > k ? i : k, lo = i > k ? k : i;
      Mc[s][f] = mfp[((size_t)(b*Nn + hi)*Nn + lo)*Ff + f];
    }
    __syncthreads();
    if (tid < Ff) {
      float sAcc = 0.f;
      for (int s = 0; s < nn; ++s) sAcc += Mc[s][tid];  // ascending k order
      aggL[tid] = sAcc;
    }
    __syncthreads();
    for (int q = tid; q < P; q += 256) {
      int jl = q >> 5, f = q & 31;
      moL[jl][f] = aggL[f] - Mc[jslotL[jl]][f];
    }
    __syncthreads();
  }

  int NR = (P + 255) >> 8;
  for (int r = 0; r < NR; ++r) {
    int p = tid + (r << 8);
    bool act = p < P;
    int jl = act ? (p >> 5) : 0;
    int f = p & 31;
    int j = jlistL[jl];
    int jslot = jslotL[jl];
    size_t eoff = ((size_t)(b*Nn + i)*Nn + j)*Ff + f;

    float z = 0.f, gs = 0.f;
    if (act) {
      float wb = wzxb[eoff];
      if (first) {
        z = sigmoidf_(wb);
      } else {
        const float4* u4 = (const float4*)&u_z[(((size_t)i*Nn + j)*Ff + f)*Ff];
        float4 u[8];
#pragma unroll
        for (int q=0;q<8;++q) u[q] = u4[q];
        z = sigmoidf_(wb + dot32(u, moL[jl]));
        // exact gate loop over neighbors (ascending k; per-dot order fixed)
#pragma unroll 2
        for (int k = 0; k < nn; ++k) {
          float v = wb + dot32(u, Mc[k]);
          if (k != jslot && v >= 16.0f && (v > 17.5f || sigmoidf_(v) >= 1.0f))
            gs += Mc[k][f];
        }
      }
      gsL[jl][f] = gs;
    }
    // per-jl-row gate detection (each jl row = one aligned half-wave)
    unsigned long long bal = __ballot(act && gs != 0.0f);
    bool rowfire = ((bal >> (tid & 32)) & 0xFFFFFFFFull) != 0ull;
    __syncthreads();

    float4 uc[8];
    if (act && rowfire) {
      const float4* uc4 = (const float4*)&u_c[(((size_t)i*Nn + j)*Ff + f)*Ff];
#pragma unroll
      for (int q=0;q<8;++q) uc[q]=uc4[q];
      rmL[jl][f] = dot32(uc, gsL[jl]);
    }
    __syncthreads();
    float d2 = 0.f;
    if (act && rowfire) d2 = dot32(uc, rmL[jl]);

    if (act) {
      float mo = first ? 0.f : moL[jl][f];
      float cur = tanhf(wcxb[eoff] + d2);
      mfn[eoff] = (1.0f - z)*mo + z*cur;
    }
    __syncthreads();
  }
}

// ---- msg_sum gather + enc = relu(u_node.x + u_msg.msg_sum) ----
__global__ __launch_bounds__(64) void finalize_enc(
    const float* __restrict__ x,
    const float* __restrict__ A,
    const float* __restrict__ mf,
    const float* __restrict__ u_node,
    const float* __restrict__ u_msg,
    float* __restrict__ enc) {
  int bi = blockIdx.x;
  int b = bi >> 6, i = bi & 63;
  int l = threadIdx.x, f = l & 31, h = l >> 5;

  float a = A[(b*Nn + i)*Nn + l];
  unsigned long long mask = __ballot(a != 0.0f);
  float acc = 0.f;
  unsigned long long mm = mask;
  int idx = 0;
  while (mm) {
    int k = __builtin_ctzll(mm);
    mm &= mm - 1;
    if ((idx & 1) == h) {
      int hi = i > k ? i : k, lo = i > k ? k : i;
      acc += mf[((size_t)(b*Nn + hi)*Nn + lo)*Ff + f];
    }
    idx++;
  }
  float accO = __shfl(acc, l ^ 32);
  acc += accO;

  __shared__ __align__(16) float vecL[2][Ff];
  if (l < 32) { vecL[0][l] = x[(b*Nn + i)*Ff + l]; vecL[1][l] = acc; }
  __syncthreads();
  const float* Urow = (h == 0) ? &u_node[((size_t)i*Ff + f)*Ff]
                               : &u_msg [((size_t)i*Ff + f)*Ff];
  const float4* w4 = (const float4*)Urow;
  float4 w[8];
#pragma unroll
  for (int q=0;q<8;++q) w[q]=w4[q];
  float d = dot32(w, vecL[h]);
  float dO = __shfl(d, l ^ 32);
  if (l < 32) enc[(b*Nn + i)*Ff + f] = fmaxf(d + dO, 0.0f);
}

// ---- output linear + sigmoid ----
__global__ void linear_out(const float* __restrict__ enc,
                           const float* __restrict__ lin_w,
                           const float* __restrict__ lin_b,
                           float* __restrict__ out) {
  int b = blockIdx.x;   // 8
  int o = threadIdx.x;  // 128
  __shared__ __align__(16) float eL[Nn*Ff];
  for (int c = o; c < Nn*Ff; c += 128) eL[c] = enc[b*Nn*Ff + c];
  __syncthreads();
  float acc = lin_b[o];
  const float4* w4 = (const float4*)&lin_w[(size_t)o*Nn*Ff];
  const float4* e4 = (const float4*)eL;
  for (int q = 0; q < (Nn*Ff)/4; ++q) {
    float4 w = w4[q], e = e4[q];
    acc = fmaf(w.x,e.x,acc); acc = fmaf(w.y,e.y,acc);
    acc = fmaf(w.z,e.z,acc); acc = fmaf(w.w,e.w,acc);
  }
  out[b*OUTn + o] = 1.0f/(1.0f+expf(-acc));
}

extern "C" void kernel_launch(void* const* d_in, const int* in_sizes, int n_in,
                              void* d_out, int out_size, void* d_ws, size_t ws_size,
                              hipStream_t stream) {
  const float* x      = (const float*)d_in[0];
  const float* A      = (const float*)d_in[1];
  const float* w_z    = (const float*)d_in[2];
  const float* w_c    = (const float*)d_in[3];
  const float* u_z    = (const float*)d_in[4];
  const float* u_c    = (const float*)d_in[5];
  const float* b_z    = (const float*)d_in[6];
  const float* b_c    = (const float*)d_in[7];
  const float* u_node = (const float*)d_in[8];
  const float* u_msg  = (const float*)d_in[9];
  const float* lin_w  = (const float*)d_in[10];
  const float* lin_b  = (const float*)d_in[11];
  float* out = (float*)d_out;
  float* ws  = (float*)d_ws;

  const size_t SZ = (size_t)Bb*Nn*Nn*Ff;  // 1,048,576 floats
  float* wzxb = ws;
  float* wcxb = ws + SZ;
  float* mf0  = ws + 2*SZ;
  float* mf1  = ws + 3*SZ;
  float* enc  = ws + 4*SZ;

  precompute_pair<<<NPAIR, 64, 0, stream>>>(x, w_z, w_c, b_z, b_c, wzxb, wcxb);

  const float* rd = mf0; float* wr = mf1;
  for (int t = 0; t < Tt; ++t) {
    edge_update<<<dim3(Bb, Nn, 2), 256, 0, stream>>>(A, u_z, u_c, wzxb, wcxb,
                                                     rd, wr, t == 0 ? 1 : 0);
    float* tmp = (float*)rd; rd = wr; wr = tmp;
  }
  finalize_enc<<<Bb*Nn, 64, 0, stream>>>(x, A, rd, u_node, u_msg, enc);
  linear_out<<<Bb, 128, 0, stream>>>(enc, lin_w, lin_b, out);
}

// Round 5
// 141.405 us; speedup vs baseline: 4.0917x; 1.2656x over previous
//
#include <hip/hip_runtime.h>
#include <math.h>

#define Bb 8
#define Nn 64
#define Ff 32
#define Tt 4
#define OUTn 128
#define NPAIR 2016   // 64*63/2 lower-triangle pairs (i>j)

__device__ __forceinline__ float sigmoidf_(float x){ return 1.0f/(1.0f+expf(-x)); }

__device__ __forceinline__ void p2ij(int p, int& i, int& j){
  int ii = (int)((1.0f + sqrtf(1.0f + 8.0f*(float)p)) * 0.5f);
  while (ii*(ii-1)/2 > p) --ii;
  while ((ii+1)*ii/2 <= p) ++ii;
  i = ii; j = p - ii*(ii-1)/2;
}

// sequential-order fp32 dot (bit-identical to the validated round-0 ordering;
// the floor(sigmoid) gate is discontinuous -> this order must not change)
__device__ __forceinline__ float dot32(const float4* __restrict__ u, const float* __restrict__ v){
  const float4* v4 = (const float4*)v;
  float d = 0.f;
#pragma unroll
  for (int q=0;q<8;++q){
    float4 a=u[q], b=v4[q];
    d = fmaf(a.x,b.x,d); d = fmaf(a.y,b.y,d);
    d = fmaf(a.z,b.z,d); d = fmaf(a.w,b.w,d);
  }
  return d;
}

// ---- precompute wzxb/wcxb for lower-tri pairs + fused t=0 update ----
// t=0: M=0 -> m_other=0, gated_sum=0 (gate*M = 0), r_msg=0
//   => m_full0 = sigmoid(wzxb) * tanh(wcxb)   (bit-exact)
__global__ __launch_bounds__(64) void precompute_pair(
    const float* __restrict__ x,
    const float* __restrict__ w_z,
    const float* __restrict__ w_c,
    const float* __restrict__ b_z,
    const float* __restrict__ b_c,
    float* __restrict__ wzxb,
    float* __restrict__ wcxb,
    float* __restrict__ mf0) {
  int p = blockIdx.x;
  int i, j; p2ij(p, i, j);
  int l = threadIdx.x, f = l & 31, h = l >> 5;

  __shared__ __align__(16) float xL[Bb][Ff];
  __shared__ __align__(16) float valL[2][Bb][Ff];
  for (int q = l; q < Bb*Ff; q += 64) {
    int b = q >> 5, g = q & 31;
    xL[b][g] = x[(b*Nn + i)*Ff + g];
  }
  __syncthreads();

  const float* W = h ? w_c : w_z;
  const float4* w4 = (const float4*)&W[(((size_t)i*Nn + j)*Ff + f)*Ff];
  float4 w[8];
#pragma unroll
  for (int q=0;q<8;++q) w[q]=w4[q];
  float bias = h ? b_c[f] : b_z[f];
  float* dst = h ? wcxb : wzxb;
#pragma unroll
  for (int b=0;b<Bb;++b){
    float v = dot32(w, xL[b]) + bias;
    dst[((size_t)(b*Nn + i)*Nn + j)*Ff + f] = v;
    valL[h][b][f] = v;
  }
  __syncthreads();
  if (h == 0) {
#pragma unroll
    for (int b=0;b<Bb;++b){
      mf0[((size_t)(b*Nn + i)*Nn + j)*Ff + f] =
          sigmoidf_(valL[0][b][f]) * tanhf(valL[1][b][f]);
    }
  }
}

// ---- one MP iteration (t>=1) over lower-tri edges; block = (b, i, j-half) ----
__global__ __launch_bounds__(256) void edge_update(
    const float* __restrict__ A,
    const float* __restrict__ u_z,
    const float* __restrict__ u_c,
    const float* __restrict__ wzxb,
    const float* __restrict__ wcxb,
    const float* __restrict__ mfp,
    float* __restrict__ mfn) {
  int b  = blockIdx.x;   // 8
  int i  = blockIdx.y;   // 64
  int jh = blockIdx.z;   // 2
  int tid = threadIdx.x;

  __shared__ __align__(16) float Mc [Nn][Ff];
  __shared__ __align__(16) float moL[32][Ff];
  __shared__ __align__(16) float gsL[32][Ff];
  __shared__ __align__(16) float rmL[32][Ff];
  __shared__ float aggL[Ff];
  __shared__ float normL[Nn];
  __shared__ int nbrL[Nn];
  __shared__ int jlistL[32], jslotL[32];
  __shared__ int nnL, jcL;

  if (tid < 64) {
    float a = A[(b*Nn + i)*Nn + tid];
    bool e = (a != 0.0f);
    unsigned long long m = __ballot(e);
    if (e) nbrL[__popcll(m & ((1ull << tid) - 1ull))] = tid;
    bool ej = e && (tid < i);
    unsigned long long mj = __ballot(ej);
    if (ej) {
      int r = __popcll(mj & ((1ull << tid) - 1ull));
      if ((r & 1) == jh) {
        int jl = r >> 1;
        jlistL[jl] = tid;
        jslotL[jl] = __popcll(m & ((1ull << tid) - 1ull));
      }
    }
    if (tid == 0) {
      nnL = __popcll(m);
      int jct = __popcll(mj);
      jcL = (jct + 1 - jh) >> 1;
    }
  }
  __syncthreads();
  int nn = nnL, jc = jcL;
  if (jc == 0) return;
  int P = jc * Ff;

  // stage compact M rows
  for (int q = tid; q < nn*Ff; q += 256) {
    int s = q >> 5, f = q & 31;
    int k = nbrL[s];
    int hi = i > k ? i : k, lo = i > k ? k : i;
    Mc[s][f] = mfp[((size_t)(b*Nn + hi)*Nn + lo)*Ff + f];
  }
  __syncthreads();
  // agg (ascending k order, matches reference sum) + per-row norms (screen)
  if (tid < Ff) {
    float sAcc = 0.f;
    for (int s = 0; s < nn; ++s) sAcc += Mc[s][tid];
    aggL[tid] = sAcc;
  }
  if (tid >= 64 && tid < 128) {
    int s = tid - 64;
    if (s < nn) {
      float ss = 0.f;
      for (int g = 0; g < Ff; ++g) { float v = Mc[s][g]; ss = fmaf(v,v,ss); }
      normL[s] = sqrtf(ss);
    }
  }
  __syncthreads();
  for (int q = tid; q < P; q += 256) {
    int jl = q >> 5, f = q & 31;
    moL[jl][f] = aggL[f] - Mc[jslotL[jl]][f];
  }
  __syncthreads();

  int NR = (P + 255) >> 8;
  for (int r = 0; r < NR; ++r) {
    int p = tid + (r << 8);
    bool act = p < P;
    int jl = act ? (p >> 5) : 0;
    int f = p & 31;
    int j = jlistL[jl];
    int jslot = jslotL[jl];
    size_t eoff = ((size_t)(b*Nn + i)*Nn + j)*Ff + f;

    float z = 0.f, gs = 0.f;
    float4 u[8];
    float wb = act ? wzxb[eoff] : -1.0e30f;
    if (act) {
      const float4* u4 = (const float4*)&u_z[(((size_t)i*Nn + j)*Ff + f)*Ff];
#pragma unroll
      for (int q=0;q<8;++q) u[q] = u4[q];
      z = sigmoidf_(wb + dot32(u, moL[jl]));
    } else {
#pragma unroll
      for (int q=0;q<8;++q) u[q] = make_float4(0.f,0.f,0.f,0.f);
    }
    // ||u_z row|| for the Cauchy-Schwarz screen (from registers)
    float un = 0.f;
#pragma unroll
    for (int q=0;q<8;++q){
      float4 a=u[q];
      un = fmaf(a.x,a.x,un); un = fmaf(a.y,a.y,un);
      un = fmaf(a.z,a.z,un); un = fmaf(a.w,a.w,un);
    }
    un = sqrtf(un);

    // gate loop: skip k wholesale when no lane can possibly reach the
    // sigmoid==1.0 region (v >= ~16.6; bound wb + ||u||*||M_k|| < 15.5)
    for (int k = 0; k < nn; ++k) {
      if (__any(wb + un * normL[k] >= 15.5f)) {
        float v = wb + dot32(u, Mc[k]);
        if (act && k != jslot && v >= 16.0f &&
            (v > 17.5f || sigmoidf_(v) >= 1.0f)) gs += Mc[k][f];
      }
    }
    if (act) gsL[jl][f] = gs;

    unsigned long long bal = __ballot(act && gs != 0.0f);
    bool rowfire = ((bal >> (tid & 32)) & 0xFFFFFFFFull) != 0ull;
    __syncthreads();

    float4 uc[8];
    if (act && rowfire) {
      const float4* uc4 = (const float4*)&u_c[(((size_t)i*Nn + j)*Ff + f)*Ff];
#pragma unroll
      for (int q=0;q<8;++q) uc[q]=uc4[q];
      rmL[jl][f] = dot32(uc, gsL[jl]);
    }
    __syncthreads();
    float d2 = 0.f;
    if (act && rowfire) d2 = dot32(uc, rmL[jl]);

    if (act) {
      float cur = tanhf(wcxb[eoff] + d2);
      mfn[eoff] = (1.0f - z)*moL[jl][f] + z*cur;
    }
    __syncthreads();
  }
}

// ---- msg_sum gather + enc = relu(u_node.x + u_msg.msg_sum) ----
__global__ __launch_bounds__(64) void finalize_enc(
    const float* __restrict__ x,
    const float* __restrict__ A,
    const float* __restrict__ mf,
    const float* __restrict__ u_node,
    const float* __restrict__ u_msg,
    float* __restrict__ enc) {
  int bi = blockIdx.x;
  int b = bi >> 6, i = bi & 63;
  int l = threadIdx.x, f = l & 31, h = l >> 5;

  float a = A[(b*Nn + i)*Nn + l];
  unsigned long long mask = __ballot(a != 0.0f);
  float acc = 0.f;
  unsigned long long mm = mask;
  int idx = 0;
  while (mm) {
    int k = __builtin_ctzll(mm);
    mm &= mm - 1;
    if ((idx & 1) == h) {
      int hi = i > k ? i : k, lo = i > k ? k : i;
      acc += mf[((size_t)(b*Nn + hi)*Nn + lo)*Ff + f];
    }
    idx++;
  }
  float accO = __shfl(acc, l ^ 32);
  acc += accO;

  __shared__ __align__(16) float vecL[2][Ff];
  if (l < 32) { vecL[0][l] = x[(b*Nn + i)*Ff + l]; vecL[1][l] = acc; }
  __syncthreads();
  const float* Urow = (h == 0) ? &u_node[((size_t)i*Ff + f)*Ff]
                               : &u_msg [((size_t)i*Ff + f)*Ff];
  const float4* w4 = (const float4*)Urow;
  float4 w[8];
#pragma unroll
  for (int q=0;q<8;++q) w[q]=w4[q];
  float d = dot32(w, vecL[h]);
  float dO = __shfl(d, l ^ 32);
  if (l < 32) enc[(b*Nn + i)*Ff + f] = fmaxf(d + dO, 0.0f);
}

// ---- output linear + sigmoid: one wave per (b, o) output element ----
__global__ __launch_bounds__(64) void linear_out(
    const float* __restrict__ enc,
    const float* __restrict__ lin_w,
    const float* __restrict__ lin_b,
    float* __restrict__ out) {
  int b = blockIdx.x >> 7;        // 8
  int o = blockIdx.x & 127;       // 128
  int l = threadIdx.x;            // 64
  const float4* w4 = (const float4*)&lin_w[(size_t)o*(Nn*Ff)];
  const float4* e4 = (const float4*)&enc[(size_t)b*(Nn*Ff)];
  float acc = 0.f;
#pragma unroll
  for (int q = 0; q < 8; ++q) {
    float4 w = w4[q*64 + l], e = e4[q*64 + l];
    acc = fmaf(w.x,e.x,acc); acc = fmaf(w.y,e.y,acc);
    acc = fmaf(w.z,e.z,acc); acc = fmaf(w.w,e.w,acc);
  }
  acc += __shfl_xor(acc, 1);  acc += __shfl_xor(acc, 2);
  acc += __shfl_xor(acc, 4);  acc += __shfl_xor(acc, 8);
  acc += __shfl_xor(acc, 16); acc += __shfl_xor(acc, 32);
  if (l == 0) out[b*OUTn + o] = sigmoidf_(acc + lin_b[o]);
}

extern "C" void kernel_launch(void* const* d_in, const int* in_sizes, int n_in,
                              void* d_out, int out_size, void* d_ws, size_t ws_size,
                              hipStream_t stream) {
  const float* x      = (const float*)d_in[0];
  const float* A      = (const float*)d_in[1];
  const float* w_z    = (const float*)d_in[2];
  const float* w_c    = (const float*)d_in[3];
  const float* u_z    = (const float*)d_in[4];
  const float* u_c    = (const float*)d_in[5];
  const float* b_z    = (const float*)d_in[6];
  const float* b_c    = (const float*)d_in[7];
  const float* u_node = (const float*)d_in[8];
  const float* u_msg  = (const float*)d_in[9];
  const float* lin_w  = (const float*)d_in[10];
  const float* lin_b  = (const float*)d_in[11];
  float* out = (float*)d_out;
  float* ws  = (float*)d_ws;

  const size_t SZ = (size_t)Bb*Nn*Nn*Ff;  // 1,048,576 floats
  float* wzxb = ws;
  float* wcxb = ws + SZ;
  float* mf0  = ws + 2*SZ;
  float* mf1  = ws + 3*SZ;
  float* enc  = ws + 4*SZ;

  // t=0 fused into precompute
  precompute_pair<<<NPAIR, 64, 0, stream>>>(x, w_z, w_c, b_z, b_c,
                                            wzxb, wcxb, mf0);

  const float* rd = mf0; float* wr = mf1;
  for (int t = 1; t < Tt; ++t) {
    edge_update<<<dim3(Bb, Nn, 2), 256, 0, stream>>>(A, u_z, u_c, wzxb, wcxb,
                                                     rd, wr);
    float* tmp = (float*)rd; rd = wr; wr = tmp;
  }
  finalize_enc<<<Bb*Nn, 64, 0, stream>>>(x, A, rd, u_node, u_msg, enc);
  linear_out<<<Bb*OUTn, 64, 0, stream>>>(enc, lin_w, lin_b, out);
}